// Round 7
// baseline (604.734 us; speedup 1.0000x reference)
//
#include <hip/hip_runtime.h>
#include <hip/hip_bf16.h>

// HarmonicFullyConnectedTensorProduct, lmax=2, MUL=64, B=1024, 11 paths.
// out[z,w,k] += sum_{u,v,m,n} x1[z,u,m] x2[z,v,n] W[p,w,u,v] C_p[m,n,k]
//
// Round 7: round-6 structure (barrier-free u-loop) with the LDS overflow fixed.
//   K1 separate GEMMs per path: D_k[w,z] += W_u[w,v] * T_k[z,v].
//   Wave owns 16 z (cols) and all 64 w rows (4 row-tiles) for all k.
//   - x2 in registers (bf16-packed when N1=5), reused across all u.
//   - c1 slab (bf16) in LDS, built cooperatively per UH u's (UH*KNP=128
//     always -> uniform 36352 B LDS for every path; the round-6 bug was
//     KNP=32 with UH=8 overflowing the smem array).
//   - T_k produced in-wave, transposed via per-wave LDS scratch: same-wave
//     ds_write->ds_read is HW-ordered; asm memory barrier stops compiler
//     reordering. No s_barrier in the u-loop.
//   - A-frags (bf16 W, [p][u][w][v] prep layout) loaded straight from L2.
// Block = 4 waves (64 z) x u-chunk of 16 -> 11 paths x 16 zgrp x 4 usub = 704.

#define NTHREADS 256
#define SMEM_BYTES 36352

typedef __attribute__((ext_vector_type(4))) float f32x4;
typedef __attribute__((ext_vector_type(8))) short s16x8;

__device__ __forceinline__ unsigned short f2bf(float x) {
    union { float f; unsigned u; } v; v.f = x;
    unsigned r = v.u + 0x7fffu + ((v.u >> 16) & 1u);   // RNE
    return (unsigned short)(r >> 16);
}
__device__ __forceinline__ float bf2f(unsigned short h) {
    union { unsigned u; float f; } v; v.u = ((unsigned)h) << 16;
    return v.f;
}
__device__ __forceinline__ unsigned pack2bf(float a, float b) {
    union { __hip_bfloat162 h; unsigned u; } v;
    v.h = __float22bfloat162_rn(make_float2(a, b));
    return v.u;
}
__device__ __forceinline__ float unpk_lo(unsigned pd) {
    union { unsigned u; float f; } v; v.u = pd << 16; return v.f;
}
__device__ __forceinline__ float unpk_hi(unsigned pd) {
    union { unsigned u; float f; } v; v.u = pd & 0xffff0000u; return v.f;
}

// ---------------- prep: W fp32 [p][w][u][v] -> bf16 [p][u][w][v] ----------------

__global__ __launch_bounds__(NTHREADS) void prep_w(const float* __restrict__ W,
                                                   unsigned short* __restrict__ Wb)
{
    int id = blockIdx.x * NTHREADS + threadIdx.x;   // (p,u,w,v4): 11*64*64*16
    int v4 = (id & 15) << 2;
    int w  = (id >> 4) & 63;
    int u  = (id >> 10) & 63;
    int p  = id >> 16;
    float4 f = *(const float4*)(W + (((size_t)p * 64 + w) * 64 + u) * 64 + v4);
    ushort4 h;
    h.x = f2bf(f.x); h.y = f2bf(f.y); h.z = f2bf(f.z); h.w = f2bf(f.w);
    *(ushort4*)(Wb + (((size_t)p * 64 + u) * 64 + w) * 64 + v4) = h;
}

// ---------------- main ----------------

struct KArgs {
    const float*          x1[3];
    const float*          x2[3];
    const unsigned short* Wb;
    const float*          C[11];
    float*                out;
};

template <int M1, int N1, int K1, int KOFF, int KNP, int UH>
__device__ __forceinline__ void run_path(const float* __restrict__ x1g,
                                         const float* __restrict__ x2g,
                                         const unsigned short* __restrict__ Wbp,
                                         const float* __restrict__ Cg,
                                         float* __restrict__ outg, int local,
                                         char* __restrict__ smem)
{
    constexpr int KN   = K1 * N1;
    constexpr int NB   = KNP / 8;          // b128 reads per (z,u) c1 row
    constexpr int ZSTR = UH * KNP + 8;     // = 136 for all paths
    static_assert(UH * KNP == 128, "slab size must be uniform");
    static_assert(KN <= KNP, "");

    float*          sC  = (float*)smem;                          // [<=125]
    unsigned short* sc1 = (unsigned short*)(smem + 512);         // [64][136]
    unsigned short* sT  = (unsigned short*)(smem + 512 + 64 * ZSTR * 2);
    // sT: per wave, 2 k-slices: [4][2][16][72] -> 18432 B; total 36352 B.

    const int t = threadIdx.x, lane = t & 63, wave = t >> 6;
    const int ln = lane & 15, q = lane >> 4;
    const int zgrp = local & 15;
    const int usub = local >> 4;
    const int z0 = zgrp * 64;              // block z base
    const int u0 = usub * 16;              // block u base
    const int zl = wave * 16 + ln;         // this lane's z (local)

    for (int i = t; i < M1 * N1 * K1; i += NTHREADS) sC[i] = Cg[i];

    // ---- x2 for (z = zl, v = q*16 .. q*16+15)
    const float* xb = x2g + (size_t)(z0 + zl) * 64 * N1 + q * 16 * N1;
    unsigned xp[N1 == 5 ? 40 : 1];         // bf16-packed (N1==5; 16B-aligned rows)
    float    xr[N1 == 5 ? 1 : 16 * N1];    // fp32 (N1<=3; scalar loads, no UB)
    if constexpr (N1 == 5) {
        float tmp[80];
#pragma unroll
        for (int j = 0; j < 20; ++j) {
            float4 f = *(const float4*)(xb + j * 4);
            tmp[j * 4 + 0] = f.x; tmp[j * 4 + 1] = f.y;
            tmp[j * 4 + 2] = f.z; tmp[j * 4 + 3] = f.w;
        }
#pragma unroll
        for (int j = 0; j < 40; ++j) xp[j] = pack2bf(tmp[2 * j], tmp[2 * j + 1]);
    } else {
#pragma unroll
        for (int j = 0; j < 16 * N1; ++j) xr[j] = xb[j];
    }

    f32x4 acc[4][K1];
#pragma unroll
    for (int wt = 0; wt < 4; ++wt)
#pragma unroll
        for (int k = 0; k < K1; ++k) acc[wt][k] = (f32x4){0.f, 0.f, 0.f, 0.f};

    unsigned short* myT = sT + wave * (2 * 16 * 72);

    __syncthreads();

#pragma unroll 1
    for (int hb = 0; hb < 16 / UH; ++hb) {
        const int ub = u0 + hb * UH;

        // ---- build c1 slab (bf16): sc1[z][uu*KNP + k*N1+n], UH u's
        for (int i = t; i < 64 * UH * KN; i += NTHREADS) {
            int z  = i / (UH * KN);
            int r  = i - z * (UH * KN);
            int uu = r / KN;
            int j  = r - uu * KN;
            int k  = j / N1, n = j - k * N1;
            const float* x1r = x1g + ((size_t)(z0 + z) * 64 + ub + uu) * M1;
            float s = 0.f;
#pragma unroll
            for (int m = 0; m < M1; ++m) s += x1r[m] * sC[(m * N1 + n) * K1 + k];
            sc1[z * ZSTR + uu * KNP + j] = f2bf(s);
        }
        __syncthreads();

        // ---- barrier-free u-loop
#pragma unroll 1
        for (int uu = 0; uu < UH; ++uu) {
            const int u = ub + uu;

            // A-frags straight from L2: Wb[u][wt*16+ln][s2*32+q*8]
            const unsigned short* wsrc = Wbp + (size_t)u * 4096;
            s16x8 af[4][2];
#pragma unroll
            for (int wt = 0; wt < 4; ++wt)
#pragma unroll
                for (int s2 = 0; s2 < 2; ++s2)
                    af[wt][s2] = *(const s16x8*)(wsrc + (wt * 16 + ln) * 64 + s2 * 32 + q * 8);

            // c1 row for (z=zl, u): KN bf16 (b128, 16B-aligned)
            const unsigned short* cb = sc1 + zl * ZSTR + uu * KNP;
            s16x8 cr[NB];
#pragma unroll
            for (int b = 0; b < NB; ++b) cr[b] = *(const s16x8*)(cb + b * 8);
            float c1v[KN];
#pragma unroll
            for (int j = 0; j < KN; ++j) c1v[j] = bf2f((unsigned short)cr[j >> 3][j & 7]);

            // per k: T (16 v per lane) -> per-wave LDS slice -> B-frags -> MFMA
#pragma unroll
            for (int k = 0; k < K1; ++k) {
                unsigned d[8];
#pragma unroll
                for (int i = 0; i < 8; ++i) {
                    float s0 = 0.f, s1 = 0.f;
#pragma unroll
                    for (int n = 0; n < N1; ++n) {
                        float cv = c1v[k * N1 + n];
                        if constexpr (N1 == 5) {
                            int e0 = (2 * i) * 5 + n, e1 = (2 * i + 1) * 5 + n;
                            float a0 = (e0 & 1) ? unpk_hi(xp[e0 >> 1]) : unpk_lo(xp[e0 >> 1]);
                            float a1 = (e1 & 1) ? unpk_hi(xp[e1 >> 1]) : unpk_lo(xp[e1 >> 1]);
                            s0 += a0 * cv; s1 += a1 * cv;
                        } else {
                            s0 += xr[(2 * i) * N1 + n] * cv;
                            s1 += xr[(2 * i + 1) * N1 + n] * cv;
                        }
                    }
                    d[i] = pack2bf(s0, s1);
                }
                unsigned short* slice = myT + (k & 1) * (16 * 72);
                *(uint4*)&slice[ln * 72 + q * 16] = make_uint4(d[0], d[1], d[2], d[3]);
                *(uint4*)&slice[ln * 72 + q * 16 + 8] = make_uint4(d[4], d[5], d[6], d[7]);
                // HW DS ops are in-order per wave; stop compiler reordering only.
                asm volatile("" ::: "memory");
                s16x8 bf0 = *(const s16x8*)&slice[ln * 72 + q * 8];
                s16x8 bf1 = *(const s16x8*)&slice[ln * 72 + 32 + q * 8];
#pragma unroll
                for (int wt = 0; wt < 4; ++wt) {
                    acc[wt][k] = __builtin_amdgcn_mfma_f32_16x16x32_bf16(
                        af[wt][0], bf0, acc[wt][k], 0, 0, 0);
                    acc[wt][k] = __builtin_amdgcn_mfma_f32_16x16x32_bf16(
                        af[wt][1], bf1, acc[wt][k], 0, 0, 0);
                }
            }
        }
        __syncthreads();
    }

    // ---- epilogue: D_k row = w = wt*16+q*4+r, col = ln -> z = z0+zl
#pragma unroll
    for (int wt = 0; wt < 4; ++wt) {
#pragma unroll
        for (int k = 0; k < K1; ++k) {
            float* op = outg + (size_t)(z0 + zl) * 576 + KOFF + k;
#pragma unroll
            for (int r = 0; r < 4; ++r)
                atomicAdd(op + (wt * 16 + q * 4 + r) * 9, acc[wt][k][r]);
        }
    }
}

__global__ __launch_bounds__(NTHREADS, 2) void tp_main(KArgs a)
{
    __shared__ __align__(16) char smem[SMEM_BYTES];

    const int bid = blockIdx.x;
    const int idx = bid >> 6;        // 64 blocks per path, heavy-first order
    const int local = bid & 63;

    switch (idx) {            //  M1 N1 K1 KOFF KNP UH
        case 0:  run_path<1,5,5,4,32, 4>(a.x1[0], a.x2[2], a.Wb + (size_t) 2*262144, a.C[2],  a.out, local, smem); break;
        case 1:  run_path<5,5,5,4,32, 4>(a.x1[2], a.x2[2], a.Wb + (size_t)10*262144, a.C[10], a.out, local, smem); break;
        case 2:  run_path<3,3,5,4,16, 8>(a.x1[1], a.x2[1], a.Wb + (size_t) 5*262144, a.C[5],  a.out, local, smem); break;
        case 3:  run_path<3,5,3,1,16, 8>(a.x1[1], a.x2[2], a.Wb + (size_t) 6*262144, a.C[6],  a.out, local, smem); break;
        case 4:  run_path<5,3,3,1,16, 8>(a.x1[2], a.x2[1], a.Wb + (size_t) 8*262144, a.C[8],  a.out, local, smem); break;
        case 5:  run_path<1,3,3,1,16, 8>(a.x1[0], a.x2[1], a.Wb + (size_t) 1*262144, a.C[1],  a.out, local, smem); break;
        case 6:  run_path<5,1,5,4, 8,16>(a.x1[2], a.x2[0], a.Wb + (size_t) 7*262144, a.C[7],  a.out, local, smem); break;
        case 7:  run_path<3,1,3,1, 8,16>(a.x1[1], a.x2[0], a.Wb + (size_t) 3*262144, a.C[3],  a.out, local, smem); break;
        case 8:  run_path<5,5,1,0, 8,16>(a.x1[2], a.x2[2], a.Wb + (size_t) 9*262144, a.C[9],  a.out, local, smem); break;
        case 9:  run_path<3,3,1,0, 8,16>(a.x1[1], a.x2[1], a.Wb + (size_t) 4*262144, a.C[4],  a.out, local, smem); break;
        case 10: run_path<1,1,1,0, 8,16>(a.x1[0], a.x2[0], a.Wb + (size_t) 0*262144, a.C[0],  a.out, local, smem); break;
        default: break;
    }
}

// ---------------- launch ----------------

extern "C" void kernel_launch(void* const* d_in, const int* in_sizes, int n_in,
                              void* d_out, int out_size, void* d_ws, size_t ws_size,
                              hipStream_t stream)
{
    unsigned short* Wb = (unsigned short*)d_ws;   // 5.77 MB

    KArgs a;
    // dict order: x1_l0, x2_l0, x1_l1, x2_l1, x1_l2, x2_l2, W, C_0..C_10
    a.x1[0] = (const float*)d_in[0];
    a.x2[0] = (const float*)d_in[1];
    a.x1[1] = (const float*)d_in[2];
    a.x2[1] = (const float*)d_in[3];
    a.x1[2] = (const float*)d_in[4];
    a.x2[2] = (const float*)d_in[5];
    a.Wb = Wb;
    for (int p = 0; p < 11; ++p) a.C[p] = (const float*)d_in[7 + p];
    a.out = (float*)d_out;

    prep_w<<<dim3(720896 / NTHREADS), NTHREADS, 0, stream>>>((const float*)d_in[6], Wb);
    hipMemsetAsync(d_out, 0, (size_t)out_size * sizeof(float), stream);
    tp_main<<<dim3(704), NTHREADS, 0, stream>>>(a);
}

// Round 8
// 182.095 us; speedup vs baseline: 3.3210x; 3.3210x over previous
//
#include <hip/hip_runtime.h>

// HarmonicFullyConnectedTensorProduct, lmax=2, MUL=64, B=1024, 11 paths.
// out[z,w,k] += sum_{u,v,m,n} x1[z,u,m] x2[z,v,n] W[p,w,u,v] C_p[m,n,k]
//
// Round 8: R4 bulk-synchronous core + software pipelining + no atomics.
//  - sT double-buffered: iter uu does  A(u)-loads -> T-form(u+1)->sT[nxt]
//    -> MFMA(u) from sT[cur]; ONE barrier per u (R4 had 2 + W staging).
//  - A-frags (bf16 W, [p][u][w][v]) loaded straight from L2 (no sW stage).
//  - LDS <= 38.1 KB -> 4 blocks/CU (16 waves) vs R4's 3.
//  - Epilogue: plain stores of per-(path,usub) partials to ws; reduce kernel
//    sums them (kills the 125 MB atomic L2-line ping-pong seen in R4-R7).

#define NTHREADS 256
#define SMEM_BYTES 38144

typedef __attribute__((ext_vector_type(4))) float f32x4;
typedef __attribute__((ext_vector_type(8))) short s16x8;

__device__ __forceinline__ unsigned short f2bf(float x) {
    union { float f; unsigned u; } v; v.f = x;
    unsigned r = v.u + 0x7fffu + ((v.u >> 16) & 1u);   // RNE
    return (unsigned short)(r >> 16);
}

// ---------------- prep: W fp32 [p][w][u][v] -> bf16 [p][u][w][v] ----------------

__global__ __launch_bounds__(NTHREADS) void prep_w(const float* __restrict__ W,
                                                   unsigned short* __restrict__ Wb)
{
    int id = blockIdx.x * NTHREADS + threadIdx.x;   // (p,u,w,v4): 11*64*64*16
    int v4 = (id & 15) << 2;
    int w  = (id >> 4) & 63;
    int u  = (id >> 10) & 63;
    int p  = id >> 16;
    float4 f = *(const float4*)(W + (((size_t)p * 64 + w) * 64 + u) * 64 + v4);
    ushort4 h;
    h.x = f2bf(f.x); h.y = f2bf(f.y); h.z = f2bf(f.z); h.w = f2bf(f.w);
    *(ushort4*)(Wb + (((size_t)p * 64 + u) * 64 + w) * 64 + v4) = h;
}

// ---------------- main ----------------

struct KArgs {
    const float*          x1[3];
    const float*          x2[3];
    const unsigned short* Wb;
    const float*          C[11];
    float*                part[11];   // per-path partials [4 usub][1024][64][K1]
};

template <int M1, int N1, int K1, int ZT, int S1, int UC>
__device__ __forceinline__ void run_path(const float* __restrict__ x1g,
                                         const float* __restrict__ x2g,
                                         const unsigned short* __restrict__ Wbp,
                                         const float* __restrict__ Cg,
                                         float* __restrict__ partp,
                                         int local, char* __restrict__ smem)
{
    constexpr int KN   = K1 * N1;
    constexpr int NC   = ZT * K1 / 16;        // MFMA col-tiles
    constexpr bool EVEN = (NC % 2 == 0);
    constexpr int ROWT = EVEN ? 2 : 1;        // w-tiles per wave
    constexpr int COLT = EVEN ? NC / 2 : NC;  // col-tiles per wave
    constexpr int NI   = ZT / 4;              // T-form z-iters
    constexpr int SST  = UC * S1 + 4;         // sc1 z-stride (floats)
    constexpr int TROWS = ZT * K1;

    float*          sC  = (float*)smem;                        // [<=125]
    float*          sc1 = (float*)(smem + 512);                // [ZT][SST]
    unsigned short* sT0 = (unsigned short*)(smem + 512 + ZT * SST * 4);
    // sT0: 2 buffers x TROWS x 72 bf16

    const int t = threadIdx.x, lane = t & 63, wave = t >> 6;
    const int ln = lane & 15, q = lane >> 4;
    const int ztile = local >> 2, usub = local & 3;
    const int z0 = ztile * ZT, u0 = usub * 16;

    for (int i = t; i < M1 * N1 * K1; i += NTHREADS) sC[i] = Cg[i];
    __syncthreads();

    // cooperative c1 slab build: sc1[z][uu2*S1 + k*N1+n] for u in [u0+us0, +UC)
    auto build_slab = [&](int us0) {
        for (int i = t; i < ZT * UC * KN; i += NTHREADS) {
            int z   = i / (UC * KN);
            int r   = i - z * (UC * KN);
            int uu2 = r / KN;
            int j   = r - uu2 * KN;
            int k   = j / N1, n = j - k * N1;
            const float* x1r = x1g + ((size_t)(z0 + z) * 64 + u0 + us0 + uu2) * M1;
            float s = 0.f;
#pragma unroll
            for (int m = 0; m < M1; ++m) s += x1r[m] * sC[(m * N1 + n) * K1 + k];
            sc1[z * SST + uu2 * S1 + j] = s;
        }
    };

    // x2 for this thread's (z = i*4+wave, v = lane), reused across all u
    float xr[NI][N1];
#pragma unroll
    for (int i = 0; i < NI; ++i) {
        const float* xp = x2g + ((size_t)(z0 + i * 4 + wave) * 64 + lane) * N1;
#pragma unroll
        for (int n = 0; n < N1; ++n) xr[i][n] = xp[n];
    }

    // T-form for u-offset uf into buffer sTn
    auto tform = [&](int uf, unsigned short* sTn) {
        const int uus = uf & (UC - 1);
#pragma unroll
        for (int i = 0; i < NI; ++i) {
            const int z = i * 4 + wave;                 // wave-uniform
            const float4* cp = (const float4*)&sc1[z * SST + uus * S1];
            float c1v[S1];
#pragma unroll
            for (int jj = 0; jj < S1 / 4; ++jj) {
                float4 f = cp[jj];
                c1v[jj * 4 + 0] = f.x; c1v[jj * 4 + 1] = f.y;
                c1v[jj * 4 + 2] = f.z; c1v[jj * 4 + 3] = f.w;
            }
#pragma unroll
            for (int k = 0; k < K1; ++k) {
                float s = 0.f;
#pragma unroll
                for (int n = 0; n < N1; ++n) s += xr[i][n] * c1v[k * N1 + n];
                sTn[(z * K1 + k) * 72 + lane] = f2bf(s);
            }
        }
    };

    f32x4 acc[ROWT][COLT];
#pragma unroll
    for (int rt = 0; rt < ROWT; ++rt)
#pragma unroll
        for (int ci = 0; ci < COLT; ++ci) acc[rt][ci] = (f32x4){0.f, 0.f, 0.f, 0.f};

    build_slab(0);
    __syncthreads();
    tform(0, sT0);
    __syncthreads();

#pragma unroll 2
    for (int uu = 0; uu < 16; ++uu) {
        if (((uu + 1) & (UC - 1)) == 0 && (uu + 1) < 16) {
            // refill sc1 for next slab; prior readers finished before last barrier
            build_slab(uu + 1);
            __syncthreads();
        }
        const int cur = uu & 1;
        unsigned short* sTc = sT0 + cur * (TROWS * 72);
        unsigned short* sTn = sT0 + (cur ^ 1) * (TROWS * 72);

        // A-frags for THIS u straight from L2 (issued early = in-iter prefetch)
        const unsigned short* wsrc = Wbp + (size_t)(u0 + uu) * 4096;
        s16x8 areg[ROWT][2];
#pragma unroll
        for (int rt = 0; rt < ROWT; ++rt) {
            const int wt = EVEN ? ((wave >> 1) * 2 + rt) : wave;
#pragma unroll
            for (int s2 = 0; s2 < 2; ++s2)
                areg[rt][s2] = *(const s16x8*)(wsrc + (wt * 16 + ln) * 64 + s2 * 32 + q * 8);
        }

        // T-form next u (writes sTn) — overlaps with MFMA below in the pipes
        if (uu < 15) tform(uu + 1, sTn);

        // MFMA from sTc
#pragma unroll
        for (int ci = 0; ci < COLT; ++ci) {
            const int c = EVEN ? ((wave & 1) * COLT + ci) : ci;
            s16x8 bf0 = *(const s16x8*)&sTc[(c * 16 + ln) * 72 + q * 8];
            s16x8 bf1 = *(const s16x8*)&sTc[(c * 16 + ln) * 72 + 32 + q * 8];
#pragma unroll
            for (int rt = 0; rt < ROWT; ++rt) {
                acc[rt][ci] = __builtin_amdgcn_mfma_f32_16x16x32_bf16(
                    areg[rt][0], bf0, acc[rt][ci], 0, 0, 0);
                acc[rt][ci] = __builtin_amdgcn_mfma_f32_16x16x32_bf16(
                    areg[rt][1], bf1, acc[rt][ci], 0, 0, 0);
            }
        }
        __syncthreads();
    }

    // ---- epilogue: plain stores to per-(path,usub) partials (no atomics)
#pragma unroll
    for (int rt = 0; rt < ROWT; ++rt) {
        const int wt = EVEN ? ((wave >> 1) * 2 + rt) : wave;
#pragma unroll
        for (int ci = 0; ci < COLT; ++ci) {
            const int c = EVEN ? ((wave & 1) * COLT + ci) : ci;
            const int col = c * 16 + ln;
            const int z = col / K1, k = col - z * K1;
            float* op = partp + ((size_t)(usub * 1024 + z0 + z) * 64) * K1 + k;
#pragma unroll
            for (int r = 0; r < 4; ++r)
                op[(wt * 16 + q * 4 + r) * K1] = acc[rt][ci][r];
        }
    }
}

__global__ __launch_bounds__(NTHREADS, 4) void tp_main(KArgs a)
{
    __shared__ __align__(16) char smem[SMEM_BYTES];

    const int bid = blockIdx.x;
    // heavy-first: p2,p10,p5,p7,p6 (256 ea, ZT16), then p1,p8,p3,p9,p4,p0 (128 ea, ZT32)
    const int starts[12] = {0, 256, 512, 768, 1024, 1280, 1408, 1536, 1664, 1792, 1920, 2048};
    int idx = 0;
#pragma unroll
    for (int i = 1; i < 12; ++i) idx += (bid >= starts[i]) ? 1 : 0;
    const int local = bid - starts[idx];

    switch (idx) {            //  M1 N1 K1 ZT S1 UC
        case 0:  run_path<1,5,5,16,28, 8>(a.x1[0], a.x2[2], a.Wb + (size_t) 2*262144, a.C[2],  a.part[2],  local, smem); break;
        case 1:  run_path<5,5,5,16,28, 8>(a.x1[2], a.x2[2], a.Wb + (size_t)10*262144, a.C[10], a.part[10], local, smem); break;
        case 2:  run_path<3,3,5,16,16, 8>(a.x1[1], a.x2[1], a.Wb + (size_t) 5*262144, a.C[5],  a.part[5],  local, smem); break;
        case 3:  run_path<5,1,5,16, 8,16>(a.x1[2], a.x2[0], a.Wb + (size_t) 7*262144, a.C[7],  a.part[7],  local, smem); break;
        case 4:  run_path<3,5,3,16,16, 8>(a.x1[1], a.x2[2], a.Wb + (size_t) 6*262144, a.C[6],  a.part[6],  local, smem); break;
        case 5:  run_path<1,3,3,32,12, 4>(a.x1[0], a.x2[1], a.Wb + (size_t) 1*262144, a.C[1],  a.part[1],  local, smem); break;
        case 6:  run_path<5,3,3,32,12, 4>(a.x1[2], a.x2[1], a.Wb + (size_t) 8*262144, a.C[8],  a.part[8],  local, smem); break;
        case 7:  run_path<3,1,3,32, 4,16>(a.x1[1], a.x2[0], a.Wb + (size_t) 3*262144, a.C[3],  a.part[3],  local, smem); break;
        case 8:  run_path<5,5,1,32, 8,16>(a.x1[2], a.x2[2], a.Wb + (size_t) 9*262144, a.C[9],  a.part[9],  local, smem); break;
        case 9:  run_path<3,3,1,32, 4,16>(a.x1[1], a.x2[1], a.Wb + (size_t) 4*262144, a.C[4],  a.part[4],  local, smem); break;
        case 10: run_path<1,1,1,32, 4,16>(a.x1[0], a.x2[0], a.Wb + (size_t) 0*262144, a.C[0],  a.part[0],  local, smem); break;
        default: break;
    }
}

// ---------------- reduce: sum partials into out[z][w][9] ----------------

struct RArgs {
    const float* part[11];
    float*       out;
};

__global__ __launch_bounds__(NTHREADS) void reduce_out(RArgs r)
{
    const int tid = blockIdx.x * NTHREADS + threadIdx.x;   // 65536 = z*64+w
    const int z = tid >> 6, w = tid & 63;

    float o[9];
#pragma unroll
    for (int i = 0; i < 9; ++i) o[i] = 0.f;

    {   // l3=0 (k slot 0), paths {0,4,9}, K1=1
        const int P[3] = {0, 4, 9};
#pragma unroll
        for (int pi = 0; pi < 3; ++pi) {
            const float* pp = r.part[P[pi]];
#pragma unroll
            for (int us = 0; us < 4; ++us)
                o[0] += pp[(size_t)(us * 1024 + z) * 64 + w];
        }
    }
    {   // l3=1 (slots 1..3), paths {1,3,6,8}, K1=3
        const int P[4] = {1, 3, 6, 8};
#pragma unroll
        for (int pi = 0; pi < 4; ++pi) {
            const float* pp = r.part[P[pi]];
#pragma unroll
            for (int us = 0; us < 4; ++us) {
                const float* row = pp + ((size_t)(us * 1024 + z) * 64 + w) * 3;
#pragma unroll
                for (int k = 0; k < 3; ++k) o[1 + k] += row[k];
            }
        }
    }
    {   // l3=2 (slots 4..8), paths {2,5,7,10}, K1=5
        const int P[4] = {2, 5, 7, 10};
#pragma unroll
        for (int pi = 0; pi < 4; ++pi) {
            const float* pp = r.part[P[pi]];
#pragma unroll
            for (int us = 0; us < 4; ++us) {
                const float* row = pp + ((size_t)(us * 1024 + z) * 64 + w) * 5;
#pragma unroll
                for (int k = 0; k < 5; ++k) o[4 + k] += row[k];
            }
        }
    }
    float* op = r.out + (size_t)tid * 9;
#pragma unroll
    for (int i = 0; i < 9; ++i) op[i] = o[i];
}

// ---------------- launch ----------------

extern "C" void kernel_launch(void* const* d_in, const int* in_sizes, int n_in,
                              void* d_out, int out_size, void* d_ws, size_t ws_size,
                              hipStream_t stream)
{
    static const int cumK1[11] = {0, 1, 4, 9, 12, 13, 18, 21, 26, 29, 30}; // prefix of K1

    unsigned short* Wb = (unsigned short*)d_ws;                       // 5.77 MB
    float* partbase = (float*)((char*)d_ws + (6u << 20));             // 36.7 MB

    KArgs a;
    // dict order: x1_l0, x2_l0, x1_l1, x2_l1, x1_l2, x2_l2, W, C_0..C_10
    a.x1[0] = (const float*)d_in[0];
    a.x2[0] = (const float*)d_in[1];
    a.x1[1] = (const float*)d_in[2];
    a.x2[1] = (const float*)d_in[3];
    a.x1[2] = (const float*)d_in[4];
    a.x2[2] = (const float*)d_in[5];
    a.Wb = Wb;
    RArgs rr;
    for (int p = 0; p < 11; ++p) {
        a.C[p]    = (const float*)d_in[7 + p];
        a.part[p] = partbase + (size_t)cumK1[p] * 262144;   // 4*1024*64 per K1-slot
        rr.part[p] = a.part[p];
    }
    rr.out = (float*)d_out;

    prep_w<<<dim3(720896 / NTHREADS), NTHREADS, 0, stream>>>((const float*)d_in[6], Wb);
    tp_main<<<dim3(2048), NTHREADS, 0, stream>>>(a);
    reduce_out<<<dim3(65536 / NTHREADS), NTHREADS, 0, stream>>>(rr);
}